// Round 5
// baseline (216.188 us; speedup 1.0000x reference)
//
#include <hip/hip_runtime.h>
#include <hip/hip_bf16.h>
#include <stdint.h>

// GPTQ int4 linear via bf16 MFMA. M=32, K=8192, N=8192, group=64.
// R14: barrier-free sequential streaming. R13 (LDS-staged 256B chunks,
// per-round vmcnt(0) barriers) gained only 3 us -> phased staging is
// depth-limited (2-buffer = one compute-window in flight, drained to 0 at
// every barrier). New geometry: BN=16, KSPLIT=2, grid 1024 (4 blk/CU,
// 16 waves/CU). Each block owns 16 full rows over a K-half; each lane
// STREAMS its row sequentially (16B@64B-stride per kq quad; consecutive
// ksteps consume full L2 lines) -> DRAM sees ~64 long sequential streams
// per block. K-loop has ZERO barriers: R12-proven register pipeline,
// 4-slot distance-3, ~6KB/wave continuously in flight. VGPR ~90, LDS 16KB.
// Fills (2x512 MiB = 155 us) are unconditional harness re-poison; scope
// is prep(~5) + main (45 -> target ~28).

#define KK 8192
#define NN 8192
#define KP 4096      // int32 per weight row
#define NG 128       // quant groups per row
#define NKS 256      // total ksteps (32 k each)

typedef __attribute__((ext_vector_type(8))) short short8;
typedef __attribute__((ext_vector_type(4))) float floatx4;
typedef __attribute__((ext_vector_type(4))) int int4v;

__device__ __forceinline__ unsigned pack_bf16x2(float lo, float hi) {
    union { __hip_bfloat162 h; unsigned u; } c;
    c.h = __float22bfloat162_rn(make_float2(lo, hi));
    return c.u;
}

// dequant 2 nibbles -> packed bf16x2 (RNE; w finite, no NaN path)
__device__ __forceinline__ unsigned dq2(int q, float sc, float zs) {
    float lo = fmaf((float)(q & 15),        sc, zs);
    float hi = fmaf((float)((q >> 4) & 15), sc, zs);
    unsigned ua = __float_as_uint(lo); ua += 0x7fffu + ((ua >> 16) & 1u);
    unsigned ub = __float_as_uint(hi); ub += 0x7fffu + ((ub >> 16) & 1u);
    return __builtin_amdgcn_perm(ub, ua, 0x07060302);   // [ub.hi16 : ua.hi16]
}

// blocks [0,xconv_blocks): x fp32 -> bf16 A-frags in xb; rest: out = bias.
__global__ void prep_kernel(const float* __restrict__ x, const float* __restrict__ bias,
                            ushort* __restrict__ xb, float* __restrict__ out,
                            int xconv_blocks)
{
    const int bx = blockIdx.x;
    if (bx < xconv_blocks) {
        const int tid = bx * 256 + threadIdx.x;   // 0..32767
        const int l   = tid & 63;
        const int ks  = (tid >> 6) & 255;
        const int mt  = tid >> 14;
        const int m   = (l & 15) + 16 * mt;
        const int kb  = ks * 32 + (l >> 4) * 8;
        const float* src = x + (size_t)m * KK + kb;
        const float4 a = *(const float4*)(src);
        const float4 b = *(const float4*)(src + 4);
        *(uint4*)(xb + (size_t)tid * 8) =
            make_uint4(pack_bf16x2(a.x, a.y), pack_bf16x2(a.z, a.w),
                       pack_bf16x2(b.x, b.y), pack_bf16x2(b.z, b.w));
    } else {
        const int f4 = (bx - xconv_blocks) * 256 + threadIdx.x;  // 0..65535
        const int n4 = f4 & (NN / 4 - 1);
        ((float4*)out)[f4] = ((const float4*)bias)[n4];
    }
}

// Streaming main: BN=16, KSPLIT=2, grid 1024. No K-loop barriers.
__global__ __launch_bounds__(256, 4)
void gptq_mfma_stream(const int*   __restrict__ pw,
                      const float* __restrict__ scales,
                      const float* __restrict__ zeros,
                      const ushort* __restrict__ xb,
                      float* __restrict__ out)
{
    __shared__ float sc_lds[64][16];   // [group_local][row]; wave read is
    __shared__ float zs_lds[64][16];   // 16 consecutive floats -> broadcast, free
    __shared__ float red[4][2][256];

    const int tid  = threadIdx.x;
    const int lane = tid & 63;
    const int wave = tid >> 6;
    const int kh   = blockIdx.x & 1;
    const int n0   = (blockIdx.x >> 1) * 16;
    const int nl   = lane & 15;
    const int kq   = lane >> 4;

    // ---- stage scales/zeros: 16 rows x 64 groups; zs = -z*s ----
    {
        const int r  = tid & 15;          // row: lane-consecutive -> conflict-free LDS writes
        const int gb = (tid >> 4) * 4;    // group base 0..60
        const float4 s4 = *(const float4*)(scales + (size_t)(n0 + r) * NG + kh * 64 + gb);
        const float4 z4 = *(const float4*)(zeros  + (size_t)(n0 + r) * NG + kh * 64 + gb);
        sc_lds[gb + 0][r] = s4.x; zs_lds[gb + 0][r] = -z4.x * s4.x;
        sc_lds[gb + 1][r] = s4.y; zs_lds[gb + 1][r] = -z4.y * s4.y;
        sc_lds[gb + 2][r] = s4.z; zs_lds[gb + 2][r] = -z4.z * s4.z;
        sc_lds[gb + 3][r] = s4.w; zs_lds[gb + 3][r] = -z4.w * s4.w;
    }
    __syncthreads();

    // lane (nl,kq) streams row n0+nl sequentially: 16 B at 64 B stride
    const int* pwp = pw + (size_t)(n0 + nl) * KP + kh * 2048 + kq * 4;
    const uint4* xfp = (const uint4*)xb;
    const int ksl0 = wave * 32;            // local kstep base (pw offset)
    const int ksg0 = kh * 128 + ksl0;      // global kstep base (xb index)

    floatx4 acc0 = {0.f, 0.f, 0.f, 0.f};
    floatx4 acc1 = {0.f, 0.f, 0.f, 0.f};
    int4v pb[4];
    uint4 xa0[4], xa1[4];

#pragma unroll
    for (int i = 0; i < 3; ++i) {
        pb[i]  = *(const int4v*)(pwp + (ksl0 + i) * 16);
        xa0[i] = xfp[(size_t)(0 * NKS + ksg0 + i) * 64 + lane];
        xa1[i] = xfp[(size_t)(1 * NKS + ksg0 + i) * 64 + lane];
    }

#pragma unroll 4
    for (int i = 0; i < 32; ++i) {
        const int slot = i & 3;
        if (i + 3 < 32) {
            const int ps = (i + 3) & 3;
            pb[ps]  = *(const int4v*)(pwp + (ksl0 + i + 3) * 16);
            xa0[ps] = xfp[(size_t)(0 * NKS + ksg0 + i + 3) * 64 + lane];
            xa1[ps] = xfp[(size_t)(1 * NKS + ksg0 + i + 3) * 64 + lane];
        }
        const int gl = (ksl0 + i) >> 1;    // block-local group 0..63
        const float sc = sc_lds[gl][nl];
        const float zs = zs_lds[gl][nl];

        union { uint4 v; short8 sv; } bf, a0, a1;
        const int4v p = pb[slot];
        bf.v.x = dq2(p.x, sc, zs);
        bf.v.y = dq2(p.y, sc, zs);
        bf.v.z = dq2(p.z, sc, zs);
        bf.v.w = dq2(p.w, sc, zs);
        a0.v = xa0[slot];
        a1.v = xa1[slot];
        acc0 = __builtin_amdgcn_mfma_f32_16x16x32_bf16(a0.sv, bf.sv, acc0, 0, 0, 0);
        acc1 = __builtin_amdgcn_mfma_f32_16x16x32_bf16(a1.sv, bf.sv, acc1, 0, 0, 0);
    }

    // ---- epilogue: 4-wave (K within block) LDS reduce, then atomicAdd ----
#pragma unroll
    for (int r = 0; r < 4; ++r) {
        const int row = kq * 4 + r;
        red[wave][0][row * 16 + nl] = acc0[r];
        red[wave][1][row * 16 + nl] = acc1[r];
    }
    __syncthreads();

#pragma unroll
    for (int i = 0; i < 2; ++i) {
        const int e   = i * 256 + tid;
        const int mt  = e >> 8;
        const int idx = e & 255;
        const float s = red[0][mt][idx] + red[1][mt][idx] + red[2][mt][idx] + red[3][mt][idx];
        atomicAdd(out + (size_t)(mt * 16 + (idx >> 4)) * NN + n0 + (idx & 15), s);
    }
}

// Fallback (no workspace): register-path kernel, direct fp32 x loads, atomics.
__global__ __launch_bounds__(256, 4)
void gptq_mfma_fallback(const int*   __restrict__ pw,
                        const float* __restrict__ scales,
                        const float* __restrict__ zeros,
                        const float* __restrict__ x,
                        float* __restrict__ out)
{
    __shared__ float s_lds[64][17];
    __shared__ float z_lds[64][17];
    __shared__ float red[4][2][256];

    const int tid  = threadIdx.x;
    const int lane = tid & 63;
    const int wave = tid >> 6;
    const int kh   = blockIdx.x & 1;
    const int n0   = (blockIdx.x >> 1) * 16;
    const int g0   = kh * 64;

    {
        const int r  = tid >> 4;
        const int gb = (tid & 15) * 4;
        const float4 s4 = *(const float4*)(scales + (size_t)(n0 + r) * NG + g0 + gb);
        const float4 z4 = *(const float4*)(zeros  + (size_t)(n0 + r) * NG + g0 + gb);
        s_lds[gb + 0][r] = s4.x; s_lds[gb + 1][r] = s4.y;
        s_lds[gb + 2][r] = s4.z; s_lds[gb + 3][r] = s4.w;
        z_lds[gb + 0][r] = z4.x; z_lds[gb + 1][r] = z4.y;
        z_lds[gb + 2][r] = z4.z; z_lds[gb + 3][r] = z4.w;
    }
    __syncthreads();

    const int nl = lane & 15;
    const int kq = lane >> 4;
    const int* pwp = pw + (size_t)(n0 + nl) * KP + kq * 4;
    const int ks0 = kh * 128 + wave * 32;

    auto load_xfrag = [&](int mt, int ks) -> uint4 {
        const float* src = x + (size_t)(nl + 16 * mt) * KK + ks * 32 + kq * 8;
        const float4 a = *(const float4*)(src);
        const float4 b = *(const float4*)(src + 4);
        return make_uint4(pack_bf16x2(a.x, a.y), pack_bf16x2(a.z, a.w),
                          pack_bf16x2(b.x, b.y), pack_bf16x2(b.z, b.w));
    };

    floatx4 acc0 = {0.f, 0.f, 0.f, 0.f};
    floatx4 acc1 = {0.f, 0.f, 0.f, 0.f};
    int4v pwb[4];
    uint4 x0b[4], x1b[4];

#pragma unroll
    for (int i = 0; i < 3; ++i) {
        const int ks = ks0 + i;
        pwb[i] = *(const int4v*)(pwp + ks * 16);
        x0b[i] = load_xfrag(0, ks);
        x1b[i] = load_xfrag(1, ks);
    }

#pragma unroll 4
    for (int i = 0; i < 32; ++i) {
        const int slot = i & 3;
        if (i + 3 < 32) {
            const int ks = ks0 + i + 3;
            const int ps = (i + 3) & 3;
            pwb[ps] = *(const int4v*)(pwp + ks * 16);
            x0b[ps] = load_xfrag(0, ks);
            x1b[ps] = load_xfrag(1, ks);
        }
        const int gl  = (wave * 32 + i) >> 1;
        const float sc = s_lds[gl][nl];
        const float zs = -z_lds[gl][nl] * sc;

        union { uint4 v; short8 sv; } bf, a0, a1;
        const int4v p = pwb[slot];
        bf.v.x = dq2(p.x, sc, zs);
        bf.v.y = dq2(p.y, sc, zs);
        bf.v.z = dq2(p.z, sc, zs);
        bf.v.w = dq2(p.w, sc, zs);
        a0.v = x0b[slot];
        a1.v = x1b[slot];
        acc0 = __builtin_amdgcn_mfma_f32_16x16x32_bf16(a0.sv, bf.sv, acc0, 0, 0, 0);
        acc1 = __builtin_amdgcn_mfma_f32_16x16x32_bf16(a1.sv, bf.sv, acc1, 0, 0, 0);
    }

#pragma unroll
    for (int r = 0; r < 4; ++r) {
        const int row = kq * 4 + r;
        red[wave][0][row * 16 + nl] = acc0[r];
        red[wave][1][row * 16 + nl] = acc1[r];
    }
    __syncthreads();

#pragma unroll
    for (int i = 0; i < 2; ++i) {
        const int e   = i * 256 + tid;
        const int mt  = e >> 8;
        const int idx = e & 255;
        const float s = red[0][mt][idx] + red[1][mt][idx] + red[2][mt][idx] + red[3][mt][idx];
        atomicAdd(out + (size_t)(mt * 16 + (idx >> 4)) * NN + n0 + (idx & 15), s);
    }
}

extern "C" void kernel_launch(void* const* d_in, const int* in_sizes, int n_in,
                              void* d_out, int out_size, void* d_ws, size_t ws_size,
                              hipStream_t stream) {
    const float* x      = (const float*)d_in[0];
    const int*   pw     = (const int*)  d_in[1];
    const float* scales = (const float*)d_in[2];
    const float* zeros  = (const float*)d_in[3];
    const float* bias   = (const float*)d_in[4];
    float* out = (float*)d_out;

    const size_t need = (size_t)32768 * 16;   // 512 KB of bf16 A-frags
    if (d_ws != nullptr && ws_size >= need) {
        ushort* xb = (ushort*)d_ws;
        prep_kernel<<<128 + 256, 256, 0, stream>>>(x, bias, xb, out, 128);
        gptq_mfma_stream<<<(NN / 16) * 2, 256, 0, stream>>>(pw, scales, zeros, xb, out);
    } else {
        prep_kernel<<<256, 256, 0, stream>>>(x, bias, nullptr, out, 0);
        gptq_mfma_fallback<<<1024, 256, 0, stream>>>(pw, scales, zeros, x, out);
    }
}

// Round 6
// 210.289 us; speedup vs baseline: 1.0280x; 1.0280x over previous
//
#include <hip/hip_runtime.h>
#include <hip/hip_bf16.h>
#include <stdint.h>

// GPTQ int4 linear via bf16 MFMA. M=32, K=8192, N=8192, group=64.
// R15: R13's LDS-staged structure + COUNTED vmcnt (T3/T4). R13's per-round
// __syncthreads() emitted s_waitcnt vmcnt(0): drain-to-zero sawtooth ->
// in-flight pw collapses every ~0.8us round -> effective ~3 TB/s. Fix is
// the m201 two-barrier form:
//   B1 (compute(r-1) done, safe to overwrite buf[(r+1)&1])
//   issue stage(r+1) [8x global_load_lds] + xa(r+1) [2 loads]
//   s_waitcnt vmcnt(10)   <- stage(r)+xa(r) retired; 10 newest STAY in flight
//   B2 (stage(r) visible to all waves) ; sched_barrier(0)
//   compute(r)
// In-flight pw stays ~64 KB/CU continuously -> HBM bus is the only binder.
// NOTE (R14 discovery): pw int32s hold only ONE data byte each (reference
// randint(0,256)) -> 128 MB is 75% interleaved padding; fetch irreducible,
// repack net-neutral (costs the same 128 MB read). Fills (2x512 MiB,
// ~156 us) are unconditional harness re-poison.

#define KK 8192
#define NN 8192
#define KP 4096      // int32 per weight row
#define NG 128       // quant groups per row
#define BN 128       // n per block
#define KSPLIT 8
#define NKS 256      // total ksteps
#define ROUNDS 8     // 32 block-ksteps / 4 per round

typedef __attribute__((ext_vector_type(8))) short short8;
typedef __attribute__((ext_vector_type(4))) float floatx4;
typedef __attribute__((ext_vector_type(4))) int int4v;

__device__ __forceinline__ unsigned pack_bf16x2(float lo, float hi) {
    union { __hip_bfloat162 h; unsigned u; } c;
    c.h = __float22bfloat162_rn(make_float2(lo, hi));
    return c.u;
}

// dequant 2 nibbles -> packed bf16x2 (RNE; w finite, no NaN path)
__device__ __forceinline__ unsigned dq2(int q, float sc, float zs) {
    float lo = fmaf((float)(q & 15),        sc, zs);
    float hi = fmaf((float)((q >> 4) & 15), sc, zs);
    unsigned ua = __float_as_uint(lo); ua += 0x7fffu + ((ua >> 16) & 1u);
    unsigned ub = __float_as_uint(hi); ub += 0x7fffu + ((ub >> 16) & 1u);
    return __builtin_amdgcn_perm(ub, ua, 0x07060302);   // [ub.hi16 : ua.hi16]
}

__device__ __forceinline__ void gload_lds16(const void* g, void* l) {
    __builtin_amdgcn_global_load_lds(
        (const __attribute__((address_space(1))) unsigned int*)g,
        (__attribute__((address_space(3))) unsigned int*)l, 16, 0, 0);
}

// blocks [0,xconv_blocks): x fp32 -> bf16 A-frags in xb; rest: out = bias.
__global__ void prep_kernel(const float* __restrict__ x, const float* __restrict__ bias,
                            ushort* __restrict__ xb, float* __restrict__ out,
                            int xconv_blocks)
{
    const int bx = blockIdx.x;
    if (bx < xconv_blocks) {
        const int tid = bx * 256 + threadIdx.x;   // 0..32767
        const int l   = tid & 63;
        const int ks  = (tid >> 6) & 255;
        const int mt  = tid >> 14;
        const int m   = (l & 15) + 16 * mt;
        const int kb  = ks * 32 + (l >> 4) * 8;
        const float* src = x + (size_t)m * KK + kb;
        const float4 a = *(const float4*)(src);
        const float4 b = *(const float4*)(src + 4);
        *(uint4*)(xb + (size_t)tid * 8) =
            make_uint4(pack_bf16x2(a.x, a.y), pack_bf16x2(a.z, a.w),
                       pack_bf16x2(b.x, b.y), pack_bf16x2(b.z, b.w));
    } else {
        const int f4 = (bx - xconv_blocks) * 256 + threadIdx.x;  // 0..65535
        const int n4 = f4 & (NN / 4 - 1);
        ((float4*)out)[f4] = ((const float4*)bias)[n4];
    }
}

__global__ __launch_bounds__(256, 2)
void gptq_mfma_main(const int*   __restrict__ pw,
                    const float* __restrict__ scales,
                    const float* __restrict__ zeros,
                    const ushort* __restrict__ xb,
                    float* __restrict__ out)
{
    // LDS map (bytes):
    //   [0,65536)      pwbuf[2][128 rows][256 B]   (XOR-swizzled row chunks)
    //   [65536,73728)  sc[16][128]
    //   [73728,81920)  zs[16][128]   (zs = -z*s)
    //   red overlay float[4][32][132] at [0,67584) after final barrier
    __shared__ __align__(16) unsigned char smem[81920];
    float* sc_lds = (float*)(smem + 65536);
    float* zs_lds = (float*)(smem + 73728);
    float (*red)[32][132] = (float (*)[32][132])smem;

    const int tid  = threadIdx.x;
    const int lane = tid & 63;
    const int wave = tid >> 6;
    const int kh   = blockIdx.x & (KSPLIT - 1);
    const int n0   = (blockIdx.x >> 3) * BN;
    const int nl   = lane & 15;
    const int kq   = lane >> 4;

    // ---- stage scales/zeros for 128 rows x 16 groups; zs = -z*s ----
    {
        const int rr = tid >> 1;          // n_local 0..127
        const int go = (tid & 1) * 8;     // group_local base 0 or 8
        const float* sp = scales + (size_t)(n0 + rr) * NG + kh * 16 + go;
        const float* zp = zeros  + (size_t)(n0 + rr) * NG + kh * 16 + go;
#pragma unroll
        for (int t = 0; t < 2; ++t) {
            const float4 s4 = *(const float4*)(sp + t * 4);
            const float4 z4 = *(const float4*)(zp + t * 4);
            sc_lds[(go + t*4 + 0)*128 + rr] = s4.x; zs_lds[(go + t*4 + 0)*128 + rr] = -z4.x * s4.x;
            sc_lds[(go + t*4 + 1)*128 + rr] = s4.y; zs_lds[(go + t*4 + 1)*128 + rr] = -z4.y * s4.y;
            sc_lds[(go + t*4 + 2)*128 + rr] = s4.z; zs_lds[(go + t*4 + 2)*128 + rr] = -z4.z * s4.z;
            sc_lds[(go + t*4 + 3)*128 + rr] = s4.w; zs_lds[(go + t*4 + 3)*128 + rr] = -z4.w * s4.w;
        }
    }

    // ---- pw stage source pointers: wave w stages rows 32w..32w+31 ----
    // Inst i covers rows 32w+4i..+3 (lane>>4 selects row, lane&15 the 16 B).
    // Source pre-swizzled: o = (nl*16) ^ ((row&7)<<4)  (LDS dest is linear).
    const unsigned char* gsrc[8];
    {
        const unsigned char* pwB = (const unsigned char*)pw + (size_t)kh * 2048;
#pragma unroll
        for (int i = 0; i < 8; ++i) {
            const int rl = 32 * wave + 4 * i + kq;          // row local 0..127
            const int o  = (nl * 16) ^ ((rl & 7) << 4);
            gsrc[i] = pwB + (size_t)(n0 + rl) * 16384 + o;
        }
    }

    // ---- prologue: stage round 0 into buf0; prefetch xa for round 0 ----
    {
        unsigned char* dst = smem + wave * 8192;
#pragma unroll
        for (int i = 0; i < 8; ++i)
            gload_lds16(gsrc[i], dst + i * 1024);
    }
    const uint4* xfp = (const uint4*)xb;
    uint4 xa[2][2];
    {
        const int ks = kh * 32 + wave;      // round 0 kstep for this wave
        xa[0][0] = xfp[(size_t)(0 * NKS + ks) * 64 + lane];
        xa[0][1] = xfp[(size_t)(1 * NKS + ks) * 64 + lane];
    }

    floatx4 acc[8][2];
#pragma unroll
    for (int f = 0; f < 8; ++f)
#pragma unroll
        for (int mt = 0; mt < 2; ++mt)
            acc[f][mt] = (floatx4){0.f, 0.f, 0.f, 0.f};

#pragma unroll
    for (int r = 0; r < ROUNDS; ++r) {
        // B1: everyone done computing round r-1 -> safe to overwrite buf[(r+1)&1]
        __builtin_amdgcn_s_barrier();

        if (r + 1 < ROUNDS) {
            // issue next-round staging + xa prefetch (stay in flight across B2)
            unsigned char* dst = smem + ((r + 1) & 1) * 32768 + wave * 8192;
#pragma unroll
            for (int i = 0; i < 8; ++i)
                gload_lds16(gsrc[i] + (size_t)(r + 1) * 256, dst + i * 1024);
            const int ksn = kh * 32 + (r + 1) * 4 + wave;
            xa[(r + 1) & 1][0] = xfp[(size_t)(0 * NKS + ksn) * 64 + lane];
            xa[(r + 1) & 1][1] = xfp[(size_t)(1 * NKS + ksn) * 64 + lane];
            // retire stage(r)+xa(r) (the 10 oldest); keep the 10 newest in flight
            if (r == 0)
                asm volatile("s_waitcnt vmcnt(10) lgkmcnt(0)" ::: "memory");
            else
                asm volatile("s_waitcnt vmcnt(10)" ::: "memory");
        } else {
            asm volatile("s_waitcnt vmcnt(0)" ::: "memory");
        }

        // B2: all waves' stage(r) retired -> buf[r&1] readable everywhere
        __builtin_amdgcn_s_barrier();
        __builtin_amdgcn_sched_barrier(0);

        // ---- compute this wave's kstep (4r + wave) from buf[r&1] ----
        const int gl = (r * 4 + wave) >> 1;     // block-local group
        const unsigned char* pwb = smem + (r & 1) * 32768;
        const int boff = nl * 256 + ((wave * 64 + kq * 16) ^ ((nl & 7) << 4));

        union { uint4 v; short8 sv; } a0, a1;
        a0.v = xa[r & 1][0];
        a1.v = xa[r & 1][1];
#pragma unroll
        for (int f = 0; f < 8; ++f) {
            const float sc = sc_lds[gl * 128 + f * 16 + nl];
            const float zs = zs_lds[gl * 128 + f * 16 + nl];
            const int4v p = *(const int4v*)(pwb + f * 4096 + boff);
            union { uint4 v; short8 sv; } bf;
            bf.v.x = dq2(p.x, sc, zs);
            bf.v.y = dq2(p.y, sc, zs);
            bf.v.z = dq2(p.z, sc, zs);
            bf.v.w = dq2(p.w, sc, zs);
            acc[f][0] = __builtin_amdgcn_mfma_f32_16x16x32_bf16(a0.sv, bf.sv, acc[f][0], 0, 0, 0);
            acc[f][1] = __builtin_amdgcn_mfma_f32_16x16x32_bf16(a1.sv, bf.sv, acc[f][1], 0, 0, 0);
        }
    }

    // all reads of LDS bufs done across the block before red overlays them
    __syncthreads();

    // ---- epilogue: 4-wave (K-split within block) LDS reduce, then atomicAdd ----
#pragma unroll
    for (int f = 0; f < 8; ++f)
#pragma unroll
        for (int mt = 0; mt < 2; ++mt)
#pragma unroll
            for (int rr = 0; rr < 4; ++rr)
                red[wave][mt * 16 + kq * 4 + rr][f * 16 + nl] = acc[f][mt][rr];
    __syncthreads();

#pragma unroll
    for (int j = 0; j < 16; ++j) {
        const int e = j * 256 + tid;      // 0..4095 partial elems
        const int m = e >> 7, c = e & 127;
        const float s = red[0][m][c] + red[1][m][c] + red[2][m][c] + red[3][m][c];
        atomicAdd(out + (size_t)m * NN + n0 + c, s);
    }
}

// Fallback (no workspace): register-path kernel, direct fp32 x loads, atomics.
__global__ __launch_bounds__(256, 4)
void gptq_mfma_fallback(const int*   __restrict__ pw,
                        const float* __restrict__ scales,
                        const float* __restrict__ zeros,
                        const float* __restrict__ x,
                        float* __restrict__ out)
{
    __shared__ float s_lds[64][17];
    __shared__ float z_lds[64][17];
    __shared__ float red[4][2][256];

    const int tid  = threadIdx.x;
    const int lane = tid & 63;
    const int wave = tid >> 6;
    const int kh   = blockIdx.x & 1;
    const int n0   = (blockIdx.x >> 1) * 16;
    const int g0   = kh * 64;

    {
        const int r  = tid >> 4;
        const int gb = (tid & 15) * 4;
        const float4 s4 = *(const float4*)(scales + (size_t)(n0 + r) * NG + g0 + gb);
        const float4 z4 = *(const float4*)(zeros  + (size_t)(n0 + r) * NG + g0 + gb);
        s_lds[gb + 0][r] = s4.x; s_lds[gb + 1][r] = s4.y;
        s_lds[gb + 2][r] = s4.z; s_lds[gb + 3][r] = s4.w;
        z_lds[gb + 0][r] = z4.x; z_lds[gb + 1][r] = z4.y;
        z_lds[gb + 2][r] = z4.z; z_lds[gb + 3][r] = z4.w;
    }
    __syncthreads();

    const int nl = lane & 15;
    const int kq = lane >> 4;
    const int* pwp = pw + (size_t)(n0 + nl) * KP + kq * 4;
    const int ks0 = kh * 128 + wave * 32;

    auto load_xfrag = [&](int mt, int ks) -> uint4 {
        const float* src = x + (size_t)(nl + 16 * mt) * KK + ks * 32 + kq * 8;
        const float4 a = *(const float4*)(src);
        const float4 b = *(const float4*)(src + 4);
        return make_uint4(pack_bf16x2(a.x, a.y), pack_bf16x2(a.z, a.w),
                          pack_bf16x2(b.x, b.y), pack_bf16x2(b.z, b.w));
    };

    floatx4 acc0 = {0.f, 0.f, 0.f, 0.f};
    floatx4 acc1 = {0.f, 0.f, 0.f, 0.f};
    int4v pwb[4];
    uint4 x0b[4], x1b[4];

#pragma unroll
    for (int i = 0; i < 3; ++i) {
        const int ks = ks0 + i;
        pwb[i] = *(const int4v*)(pwp + ks * 16);
        x0b[i] = load_xfrag(0, ks);
        x1b[i] = load_xfrag(1, ks);
    }

#pragma unroll 4
    for (int i = 0; i < 32; ++i) {
        const int slot = i & 3;
        if (i + 3 < 32) {
            const int ks = ks0 + i + 3;
            const int ps = (i + 3) & 3;
            pwb[ps] = *(const int4v*)(pwp + ks * 16);
            x0b[ps] = load_xfrag(0, ks);
            x1b[ps] = load_xfrag(1, ks);
        }
        const int gl  = (wave * 32 + i) >> 1;
        const float sc = s_lds[gl][nl];
        const float zs = -z_lds[gl][nl] * sc;

        union { uint4 v; short8 sv; } bf, a0, a1;
        const int4v p = pwb[slot];
        bf.v.x = dq2(p.x, sc, zs);
        bf.v.y = dq2(p.y, sc, zs);
        bf.v.z = dq2(p.z, sc, zs);
        bf.v.w = dq2(p.w, sc, zs);
        a0.v = x0b[slot];
        a1.v = x1b[slot];
        acc0 = __builtin_amdgcn_mfma_f32_16x16x32_bf16(a0.sv, bf.sv, acc0, 0, 0, 0);
        acc1 = __builtin_amdgcn_mfma_f32_16x16x32_bf16(a1.sv, bf.sv, acc1, 0, 0, 0);
    }

#pragma unroll
    for (int r = 0; r < 4; ++r) {
        const int row = kq * 4 + r;
        red[wave][0][row * 16 + nl] = acc0[r];
        red[wave][1][row * 16 + nl] = acc1[r];
    }
    __syncthreads();

#pragma unroll
    for (int i = 0; i < 2; ++i) {
        const int e   = i * 256 + tid;
        const int mt  = e >> 8;
        const int idx = e & 255;
        const float s = red[0][mt][idx] + red[1][mt][idx] + red[2][mt][idx] + red[3][mt][idx];
        atomicAdd(out + (size_t)(mt * 16 + (idx >> 4)) * NN + n0 + (idx & 15), s);
    }
}

extern "C" void kernel_launch(void* const* d_in, const int* in_sizes, int n_in,
                              void* d_out, int out_size, void* d_ws, size_t ws_size,
                              hipStream_t stream) {
    const float* x      = (const float*)d_in[0];
    const int*   pw     = (const int*)  d_in[1];
    const float* scales = (const float*)d_in[2];
    const float* zeros  = (const float*)d_in[3];
    const float* bias   = (const float*)d_in[4];
    float* out = (float*)d_out;

    const size_t need = (size_t)32768 * 16;   // 512 KB of bf16 A-frags
    if (d_ws != nullptr && ws_size >= need) {
        ushort* xb = (ushort*)d_ws;
        prep_kernel<<<128 + 256, 256, 0, stream>>>(x, bias, xb, out, 128);
        gptq_mfma_main<<<(NN / BN) * KSPLIT, 256, 0, stream>>>(pw, scales, zeros, xb, out);
    } else {
        prep_kernel<<<256, 256, 0, stream>>>(x, bias, nullptr, out, 0);
        gptq_mfma_fallback<<<1024, 256, 0, stream>>>(pw, scales, zeros, x, out);
    }
}